// Round 7
// baseline (214.829 us; speedup 1.0000x reference)
//
#include <hip/hip_runtime.h>
#include <cstdint>
#include <cstddef>

// ---------- types ----------
typedef __bf16 bf16_t;
typedef __bf16 bf16x8 __attribute__((ext_vector_type(8)));
typedef __bf16 bf16x4 __attribute__((ext_vector_type(4)));
typedef float  f32x4  __attribute__((ext_vector_type(4)));

#define MFMA_BF16(a, b, c) __builtin_amdgcn_mfma_f32_16x16x32_bf16((a), (b), (c), 0, 0, 0)

// async global->LDS, 16B per lane. LDS dest must be wave-uniform base + lane*16.
__device__ __forceinline__ void async_load16(const void* g, void* l) {
    __builtin_amdgcn_global_load_lds((const __attribute__((address_space(1))) void*)g,
                                     (__attribute__((address_space(3))) void*)l,
                                     16, 0, 0);
}

// XOR-swizzled LDS layout for a 64x64 bf16 tile stored as 16B chunks (8 chunks/row).
// chunk (r, cg) lives at slot r*8 + (cg ^ (r&7)); returns bf16 element offset.
#define SWZ(r, cg) ((((r) << 3) | ((cg) ^ ((r) & 7))) << 3)

// ---------- problem constants ----------
#define Bq   2
#define Tq   2048
#define Cq   1024
#define Hq   16
#define HSq  64
#define Mrows 4096   // B*T

// ---------- fused fp32 -> bf16 convert for x, W_qkv, W_proj ----------
__global__ __launch_bounds__(256)
void cvt_all(const float* __restrict__ x, const float* __restrict__ wqkv,
             const float* __restrict__ wproj,
             bf16_t* __restrict__ xb, bf16_t* __restrict__ wqkvb,
             bf16_t* __restrict__ wprojb) {
    size_t gid = (size_t)blockIdx.x * 256 + threadIdx.x;  // quad index
    const float* src; bf16_t* dst; size_t off;
    if (gid < 1048576)      { src = x;     dst = xb;     off = gid; }
    else if (gid < 1835008) { src = wqkv;  dst = wqkvb;  off = gid - 1048576; }
    else                    { src = wproj; dst = wprojb; off = gid - 1835008; }
    float4 v = ((const float4*)src)[off];
    bf16x4 o;
    o[0] = (bf16_t)v.x; o[1] = (bf16_t)v.y; o[2] = (bf16_t)v.z; o[3] = (bf16_t)v.w;
    *(bf16x4*)(dst + off * 4) = o;
}

// ---------- GEMM: C[m][n] = sum_k A[m][k]*B[n][k], A:[M,K], B:[N,K] row-major ----------
// EPI=1: fp32 out + bias.  EPI=2: QKV split epilogue -> Qc [4096][1024],
// Kc [32][2048][64] compact, Vt [32][64][2048] transposed.
template <int BM, int EPI>
__global__ __launch_bounds__(256)
void gemm_bt(const bf16_t* __restrict__ A, const bf16_t* __restrict__ B,
             void* __restrict__ Cout, const float* __restrict__ bias,
             bf16_t* __restrict__ qc, bf16_t* __restrict__ kc, bf16_t* __restrict__ vtp,
             int M, int N, int K) {
    constexpr int MR = BM / 32;   // MFMA row-tiles per wave
    __shared__ __align__(16) bf16_t As[BM * 32];
    __shared__ __align__(16) bf16_t Bs[128 * 32];

    const int tid  = threadIdx.x;
    const int wave = tid >> 6;
    const int lane = tid & 63;
    const int m0 = blockIdx.y * BM;
    const int n0 = blockIdx.x * 128;
    const int wm = (wave >> 1) * (BM / 2);
    const int wn = (wave & 1) * 64;
    const int lrow = lane & 15;
    const int lko  = (lane >> 4) * 8;

    f32x4 acc[MR][4] = {};

    const bf16_t* Ag = A + (size_t)m0 * K;
    const bf16_t* Bg = B + (size_t)n0 * K;
    const int c0 = tid, c1 = tid + 256;

    for (int k0 = 0; k0 < K; k0 += 32) {
        async_load16(Ag + (size_t)(c0 >> 2) * K + k0 + (c0 & 3) * 8, &As[c0 * 8]);
        if (BM == 128)
            async_load16(Ag + (size_t)(c1 >> 2) * K + k0 + (c1 & 3) * 8, &As[c1 * 8]);
        async_load16(Bg + (size_t)(c0 >> 2) * K + k0 + (c0 & 3) * 8, &Bs[c0 * 8]);
        async_load16(Bg + (size_t)(c1 >> 2) * K + k0 + (c1 & 3) * 8, &Bs[c1 * 8]);
        __syncthreads();

        bf16x8 af[MR], bfr[4];
        #pragma unroll
        for (int r = 0; r < MR; r++) af[r] = *(const bf16x8*)&As[(wm + r * 16 + lrow) * 32 + lko];
        #pragma unroll
        for (int c = 0; c < 4; c++) bfr[c] = *(const bf16x8*)&Bs[(wn + c * 16 + lrow) * 32 + lko];
        #pragma unroll
        for (int r = 0; r < MR; r++)
            #pragma unroll
            for (int c = 0; c < 4; c++)
                acc[r][c] = MFMA_BF16(af[r], bfr[c], acc[r][c]);
        __syncthreads();
    }

    const int er = (lane >> 4) * 4;
    const int ec = lane & 15;
    #pragma unroll
    for (int r = 0; r < MR; r++) {
        #pragma unroll
        for (int c = 0; c < 4; c++) {
            int m = m0 + wm + r * 16 + er;
            int n = n0 + wn + c * 16 + ec;
            if (EPI == 1) {
                #pragma unroll
                for (int v = 0; v < 4; v++)
                    ((float*)Cout)[(size_t)(m + v) * N + n] = acc[r][c][v] + bias[n];
            } else {
                int bb = m >> 11, t = m & 2047;   // block-uniform region (n0 128-aligned)
                if (n < 1024) {
                    #pragma unroll
                    for (int v = 0; v < 4; v++)
                        qc[(size_t)(m + v) * 1024 + n] = (bf16_t)acc[r][c][v];
                } else if (n < 2048) {
                    int h = (n - 1024) >> 6, d = (n - 1024) & 63;
                    bf16_t* p = kc + ((size_t)(bb * 16 + h) * Tq + t) * 64 + d;
                    #pragma unroll
                    for (int v = 0; v < 4; v++) p[v * 64] = (bf16_t)acc[r][c][v];
                } else {
                    int h = (n - 2048) >> 6, d = (n - 2048) & 63;
                    bf16x4 o;
                    #pragma unroll
                    for (int v = 0; v < 4; v++) o[v] = (bf16_t)acc[r][c][v];
                    *(bf16x4*)&vtp[((size_t)(bb * 16 + h) * 64 + d) * Tq + t] = o;
                }
            }
        }
    }
}

// ---------- attention: Q-tile 128, LDS-staged K/V, reg-prefetch, 4-way k-split ----------
// block = (bh, Qi of 128 q-rows, quarter). Wave w owns q rows [q0+32w, q0+32w+32).
// S^T = K Q^T -> softplus (log2 domain; scale cancels in O/||w||) -> per-wave Ws
// (C->A layout round-trip, pad 72) -> O += W V. Two barriers per k-tile.
// NO min-waves clamp (R5 lesson: (256,4) forced 64 VGPR -> 340 MB scratch spill).
__global__ __launch_bounds__(256)
void attn_kernel(const bf16_t* __restrict__ Qc, const bf16_t* __restrict__ Kc,
                 const bf16_t* __restrict__ Vt,
                 bf16_t* __restrict__ Op0, bf16_t* __restrict__ Op1,
                 bf16_t* __restrict__ Op2, bf16_t* __restrict__ Op3,
                 float* __restrict__ n2part) {
    __shared__ __align__(16) bf16_t Ks[64 * 64];     // swizzled [key][d]
    __shared__ __align__(16) bf16_t Vs[64 * 64];     // swizzled [d][key]
    __shared__ __align__(16) bf16_t Ws[4][32 * 72];  // per-wave private, pad 72

    const int tid = threadIdx.x;
    const int wave = tid >> 6;
    const int lane = tid & 63;
    const int lrow = lane & 15;
    const int lg   = lane >> 4;
    const int er   = lg * 4;
    const int ec   = lrow;

    const int raw     = blockIdx.x;       // 0..63, heavy-first
    const int Qi      = 15 - (raw >> 2);
    const int quarter = raw & 3;
    const int bh = blockIdx.y;
    const int b  = bh >> 4, h = bh & 15;

    const int q0 = Qi * 128;
    const int qw = q0 + wave * 32;
    const int nt = 2 * Qi + 2;
    const int lo = (quarter * nt) >> 2;
    const int hi = ((quarter + 1) * nt) >> 2;

    const bf16_t* Qb = Qc + (size_t)b * Tq * Cq + h * 64;
    const bf16_t* Kb = Kc + (size_t)bh * Tq * 64;
    const bf16_t* Vb = Vt + (size_t)bh * 64 * Tq;
    bf16_t* wsm = &Ws[wave][0];

    // Q fragments (B-operand for S^T): set t covers q = qw + 16t + lrow
    bf16x8 qf[2][2];
    #pragma unroll
    for (int t = 0; t < 2; t++)
        #pragma unroll
        for (int s = 0; s < 2; s++)
            qf[t][s] = *(const bf16x8*)&Qb[(size_t)(qw + 16 * t + lrow) * Cq + s * 32 + lg * 8];

    // staging: thread covers swizzled slots tid, tid+256 for each of K,V
    const int s0 = tid, s1 = tid + 256;
    const int r0 = s0 >> 3, cg0 = (s0 & 7) ^ (r0 & 7);
    const int r1 = s1 >> 3, cg1 = (s1 & 7) ^ (r1 & 7);

    bf16x8 kr0, kr1, vr0, vr1;
    if (lo < hi) {
        const int key0 = lo * 64;
        kr0 = *(const bf16x8*)&Kb[(size_t)(key0 + r0) * 64 + cg0 * 8];
        kr1 = *(const bf16x8*)&Kb[(size_t)(key0 + r1) * 64 + cg1 * 8];
        vr0 = *(const bf16x8*)&Vb[(size_t)r0 * Tq + key0 + cg0 * 8];
        vr1 = *(const bf16x8*)&Vb[(size_t)r1 * Tq + key0 + cg1 * 8];
    }

    f32x4 oacc[2][4] = {};
    float n2[2] = {0.f, 0.f};
    const float C1 = 0.18033688f;  // 0.125 * log2(e)

    for (int kt = lo; kt < hi; kt++) {
        const int key0 = kt * 64;
        __syncthreads();  // all waves done reading Ks/Vs of previous iter
        *(bf16x8*)&Ks[s0 * 8] = kr0;
        *(bf16x8*)&Ks[s1 * 8] = kr1;
        *(bf16x8*)&Vs[s0 * 8] = vr0;
        *(bf16x8*)&Vs[s1 * 8] = vr1;
        __syncthreads();

        if (kt + 1 < hi) {  // prefetch next tile; in flight during compute
            const int k1 = (kt + 1) * 64;
            kr0 = *(const bf16x8*)&Kb[(size_t)(k1 + r0) * 64 + cg0 * 8];
            kr1 = *(const bf16x8*)&Kb[(size_t)(k1 + r1) * 64 + cg1 * 8];
            vr0 = *(const bf16x8*)&Vb[(size_t)r0 * Tq + k1 + cg0 * 8];
            vr1 = *(const bf16x8*)&Vb[(size_t)r1 * Tq + k1 + cg1 * 8];
        }

        if (key0 <= qw + 31) {  // wave-uniform causal skip (barrier-safe)
            bf16x8 kf[4][2];
            #pragma unroll
            for (int j = 0; j < 4; j++)
                #pragma unroll
                for (int s = 0; s < 2; s++)
                    kf[j][s] = *(const bf16x8*)&Ks[SWZ(16 * j + lrow, s * 4 + lg)];

            #pragma unroll
            for (int t = 0; t < 2; t++) {
                if (key0 <= qw + 16 * t + 15) {
                    f32x4 sacc[4];
                    #pragma unroll
                    for (int j = 0; j < 4; j++) {
                        f32x4 z = {};
                        z = MFMA_BF16(kf[j][0], qf[t][0], z);
                        sacc[j] = MFMA_BF16(kf[j][1], qf[t][1], z);
                    }
                    const bool diagU = (key0 + 63 > qw + 16 * t);
                    const int qmine = qw + 16 * t + ec;
                    #pragma unroll
                    for (int j = 0; j < 4; j++) {
                        bf16x4 wb;
                        #pragma unroll
                        for (int v = 0; v < 4; v++) {
                            float tv = sacc[j][v] * C1;
                            float e  = __builtin_amdgcn_exp2f(-fabsf(tv));
                            float w  = fmaxf(tv, 0.f) + __builtin_amdgcn_logf(1.f + e);
                            if (diagU && (key0 + 16 * j + er + v > qmine)) w = 0.f;
                            n2[t] += w * w;
                            wb[v] = (bf16_t)w;
                        }
                        *(bf16x4*)&wsm[(16 * t + ec) * 72 + 16 * j + er] = wb;
                    }
                }
            }

            bf16x8 vf[4][2];
            #pragma unroll
            for (int jd = 0; jd < 4; jd++)
                #pragma unroll
                for (int s2 = 0; s2 < 2; s2++)
                    vf[jd][s2] = *(const bf16x8*)&Vs[SWZ(16 * jd + lrow, s2 * 4 + lg)];

            #pragma unroll
            for (int t = 0; t < 2; t++) {
                if (key0 <= qw + 16 * t + 15) {
                    #pragma unroll
                    for (int s2 = 0; s2 < 2; s2++) {
                        bf16x8 wf = *(const bf16x8*)&wsm[(16 * t + lrow) * 72 + s2 * 32 + lg * 8];
                        #pragma unroll
                        for (int jd = 0; jd < 4; jd++)
                            oacc[t][jd] = MFMA_BF16(wf, vf[jd][s2], oacc[t][jd]);
                    }
                }
            }
        }
    }

    // n2 per lane covers q = qw+16t+ec over its lg key-group; reduce across lg
    #pragma unroll
    for (int t = 0; t < 2; t++) {
        n2[t] += __shfl_xor(n2[t], 16, 64);
        n2[t] += __shfl_xor(n2[t], 32, 64);
    }

    // partial epilogue (unconditional: empty-range blocks must write zeros over poison)
    const int qiL   = Qi * 2 + (wave >> 1);
    const int rbase = 32 * (wave & 1);
    bf16_t* Op = (quarter == 0 ? Op0 : quarter == 1 ? Op1 : quarter == 2 ? Op2 : Op3)
               + ((size_t)bh * 32 + qiL) * 4096;
    #pragma unroll
    for (int t = 0; t < 2; t++)
        #pragma unroll
        for (int jd = 0; jd < 4; jd++)
            #pragma unroll
            for (int v = 0; v < 4; v++)
                Op[(rbase + 16 * t + er + v) * 64 + 16 * jd + ec] = (bf16_t)oacc[t][jd][v];
    if (lg == 0) {
        #pragma unroll
        for (int t = 0; t < 2; t++)
            n2part[((size_t)quarter * 1024 + bh * 32 + qiL) * 64 + rbase + 16 * t + ec] = n2[t];
    }
}

// ---------- combine 4 partials: ao = (ΣO) * rsqrt(Σn2) ----------
__global__ __launch_bounds__(256)
void combine_kernel(const bf16_t* __restrict__ O0, const bf16_t* __restrict__ O1,
                    const bf16_t* __restrict__ O2, const bf16_t* __restrict__ O3,
                    const float* __restrict__ n2part, bf16_t* __restrict__ ao) {
    const int qi = blockIdx.x;
    const int bh = blockIdx.y;
    const int b = bh >> 4, h = bh & 15;
    const int t = threadIdx.x;
    const size_t base = ((size_t)bh * 32 + qi) * 4096;
    const float* np = n2part + ((size_t)bh * 32 + qi) * 64;
    #pragma unroll
    for (int i = 0; i < 2; i++) {
        int idx = i * 2048 + t * 8;
        int row = idx >> 6, col = idx & 63;
        bf16x8 a0 = *(const bf16x8*)(O0 + base + idx);
        bf16x8 a1 = *(const bf16x8*)(O1 + base + idx);
        bf16x8 a2 = *(const bf16x8*)(O2 + base + idx);
        bf16x8 a3 = *(const bf16x8*)(O3 + base + idx);
        float nsum = np[row] + np[(size_t)1024 * 64 + row]
                   + np[(size_t)2048 * 64 + row] + np[(size_t)3072 * 64 + row];
        float inv = rsqrtf(nsum);
        bf16x8 o;
        #pragma unroll
        for (int j = 0; j < 8; j++)
            o[j] = (bf16_t)(((float)a0[j] + (float)a1[j] + (float)a2[j] + (float)a3[j]) * inv);
        *(bf16x8*)(ao + (size_t)(b * Tq + qi * 64 + row) * Cq + h * HSq + col) = o;
    }
}

// ---------- launch ----------
extern "C" void kernel_launch(void* const* d_in, const int* in_sizes, int n_in,
                              void* d_out, int out_size, void* d_ws, size_t ws_size,
                              hipStream_t stream) {
    const float* x     = (const float*)d_in[0];
    const float* wqkv  = (const float*)d_in[1];
    const float* wproj = (const float*)d_in[2];
    const float* bproj = (const float*)d_in[3];
    float* out = (float*)d_out;

    // workspace lifetime plan (64 MB):
    //  phase1 cvt+gemm1: wprojb[0,2) xb[2,10) wqkvb[10,16) qcb[16,24) kcb[24,32) vtb[32,40)
    //  phase2 attn:      op0 over dead xb[2,10), n2 over dead wqkvb[10,11), op1[40,48)
    //                    op2[48,56) op3[56,64)
    //  phase3 combine:   ao over dead kcb[24,32)
    //  phase4 gemm2:     reads ao[24,32) + wprojb[0,2)
    char* ws = (char*)d_ws;
    bf16_t* wprojb = (bf16_t*)(ws);
    bf16_t* xb     = (bf16_t*)(ws + ( 2u << 20));
    bf16_t* wqkvb  = (bf16_t*)(ws + (10u << 20));
    bf16_t* qcb    = (bf16_t*)(ws + (16u << 20));
    bf16_t* kcb    = (bf16_t*)(ws + (24u << 20));
    bf16_t* vtb    = (bf16_t*)(ws + (32u << 20));
    bf16_t* opart0 = (bf16_t*)(ws + ( 2u << 20));
    float*  n2part = (float*)(ws + (10u << 20));
    bf16_t* opart1 = (bf16_t*)(ws + (40u << 20));
    bf16_t* opart2 = (bf16_t*)(ws + (48u << 20));
    bf16_t* opart3 = (bf16_t*)(ws + (56u << 20));
    bf16_t* aob    = (bf16_t*)(ws + (24u << 20));

    cvt_all<<<8192, 256, 0, stream>>>(x, wqkv, wproj, xb, wqkvb, wprojb);

    // QKV projection with fused layout epilogue: Qc / Kc / V^T
    gemm_bt<128, 2><<<dim3(24, 32), 256, 0, stream>>>(xb, wqkvb, nullptr, nullptr,
                                                      qcb, kcb, vtb, Mrows, 3 * Cq, Cq);
    // attention (Q-tile 128, 4-way k-split, unclamped registers) + combine
    attn_kernel<<<dim3(64, 32), 256, 0, stream>>>(qcb, kcb, vtb,
                                                  opart0, opart1, opart2, opart3, n2part);
    combine_kernel<<<dim3(32, 32), 256, 0, stream>>>(opart0, opart1, opart2, opart3,
                                                     n2part, aob);
    // output projection + bias
    gemm_bt<64, 1><<<dim3(8, 64), 256, 0, stream>>>(aob, wprojb, (void*)out, bproj,
                                                    nullptr, nullptr, nullptr, Mrows, Cq, Cq);
}

// Round 8
// 188.017 us; speedup vs baseline: 1.1426x; 1.1426x over previous
//
#include <hip/hip_runtime.h>
#include <cstdint>
#include <cstddef>

// ---------- types ----------
typedef __bf16 bf16_t;
typedef __bf16 bf16x8 __attribute__((ext_vector_type(8)));
typedef __bf16 bf16x4 __attribute__((ext_vector_type(4)));
typedef float  f32x4  __attribute__((ext_vector_type(4)));

#define MFMA_BF16(a, b, c) __builtin_amdgcn_mfma_f32_16x16x32_bf16((a), (b), (c), 0, 0, 0)

// async global->LDS, 16B per lane. LDS dest must be wave-uniform base + lane*16.
__device__ __forceinline__ void async_load16(const void* g, void* l) {
    __builtin_amdgcn_global_load_lds((const __attribute__((address_space(1))) void*)g,
                                     (__attribute__((address_space(3))) void*)l,
                                     16, 0, 0);
}

// XOR-swizzled LDS layout for tiles with 8 16B-chunks per row (64 bf16/row).
// chunk (r, cg) lives at slot r*8 + (cg ^ (r&7)); returns bf16 element offset.
#define SWZ(r, cg) ((((r) << 3) | ((cg) ^ ((r) & 7))) << 3)

// ---------- problem constants ----------
#define Bq   2
#define Tq   2048
#define Cq   1024
#define Hq   16
#define HSq  64
#define Mrows 4096   // B*T

// ---------- fused fp32 -> bf16 convert for x, W_qkv, W_proj ----------
__global__ __launch_bounds__(256)
void cvt_all(const float* __restrict__ x, const float* __restrict__ wqkv,
             const float* __restrict__ wproj,
             bf16_t* __restrict__ xb, bf16_t* __restrict__ wqkvb,
             bf16_t* __restrict__ wprojb) {
    size_t gid = (size_t)blockIdx.x * 256 + threadIdx.x;  // quad index
    const float* src; bf16_t* dst; size_t off;
    if (gid < 1048576)      { src = x;     dst = xb;     off = gid; }
    else if (gid < 1835008) { src = wqkv;  dst = wqkvb;  off = gid - 1048576; }
    else                    { src = wproj; dst = wprojb; off = gid - 1835008; }
    float4 v = ((const float4*)src)[off];
    bf16x4 o;
    o[0] = (bf16_t)v.x; o[1] = (bf16_t)v.y; o[2] = (bf16_t)v.z; o[3] = (bf16_t)v.w;
    *(bf16x4*)(dst + off * 4) = o;
}

// ---------- GEMM: C[m][n] = sum_k A[m][k]*B[n][k], A:[M,K], B:[N,K] row-major ----------
// BK=64, XOR-swizzled LDS (breaks the 128B-stride bank pathology; staging stays
// contiguous-slot for global_load_lds). 32 MFMA per barrier-pair (vs 16 at BK=32).
// EPI=1: fp32 out + bias.  EPI=2: QKV split epilogue -> Qc [4096][1024],
// Kc [32][2048][64] compact, Vt [32][64][2048] transposed.
template <int BM, int EPI>
__global__ __launch_bounds__(256)
void gemm_bt(const bf16_t* __restrict__ A, const bf16_t* __restrict__ B,
             void* __restrict__ Cout, const float* __restrict__ bias,
             bf16_t* __restrict__ qc, bf16_t* __restrict__ kc, bf16_t* __restrict__ vtp,
             int M, int N, int K) {
    constexpr int MR = BM / 32;        // MFMA row-tiles per wave
    constexpr int ACH = BM * 8 / 256;  // A-chunks per thread (BM=128 -> 4, 64 -> 2)
    __shared__ __align__(16) bf16_t As[BM * 64];
    __shared__ __align__(16) bf16_t Bs[128 * 64];

    const int tid  = threadIdx.x;
    const int wave = tid >> 6;
    const int lane = tid & 63;
    const int m0 = blockIdx.y * BM;
    const int n0 = blockIdx.x * 128;
    const int wm = (wave >> 1) * (BM / 2);
    const int wn = (wave & 1) * 64;
    const int lrow = lane & 15;
    const int lg   = lane >> 4;

    f32x4 acc[MR][4] = {};

    const bf16_t* Ag = A + (size_t)m0 * K;
    const bf16_t* Bg = B + (size_t)n0 * K;

    for (int k0 = 0; k0 < K; k0 += 64) {
        #pragma unroll
        for (int i = 0; i < ACH; i++) {
            int s = i * 256 + tid;
            int r = s >> 3, cg = (s & 7) ^ (r & 7);
            async_load16(Ag + (size_t)r * K + k0 + cg * 8, &As[s * 8]);
        }
        #pragma unroll
        for (int i = 0; i < 4; i++) {
            int s = i * 256 + tid;
            int r = s >> 3, cg = (s & 7) ^ (r & 7);
            async_load16(Bg + (size_t)r * K + k0 + cg * 8, &Bs[s * 8]);
        }
        __syncthreads();

        #pragma unroll
        for (int kk = 0; kk < 2; kk++) {
            bf16x8 af[MR], bfr[4];
            #pragma unroll
            for (int r = 0; r < MR; r++)
                af[r] = *(const bf16x8*)&As[SWZ(wm + r * 16 + lrow, kk * 4 + lg)];
            #pragma unroll
            for (int c = 0; c < 4; c++)
                bfr[c] = *(const bf16x8*)&Bs[SWZ(wn + c * 16 + lrow, kk * 4 + lg)];
            #pragma unroll
            for (int r = 0; r < MR; r++)
                #pragma unroll
                for (int c = 0; c < 4; c++)
                    acc[r][c] = MFMA_BF16(af[r], bfr[c], acc[r][c]);
        }
        __syncthreads();
    }

    const int er = (lane >> 4) * 4;
    const int ec = lane & 15;
    #pragma unroll
    for (int r = 0; r < MR; r++) {
        #pragma unroll
        for (int c = 0; c < 4; c++) {
            int m = m0 + wm + r * 16 + er;
            int n = n0 + wn + c * 16 + ec;
            if (EPI == 1) {
                #pragma unroll
                for (int v = 0; v < 4; v++)
                    ((float*)Cout)[(size_t)(m + v) * N + n] = acc[r][c][v] + bias[n];
            } else {
                int bb = m >> 11, t = m & 2047;   // block-uniform region (n0 128-aligned)
                if (n < 1024) {
                    #pragma unroll
                    for (int v = 0; v < 4; v++)
                        qc[(size_t)(m + v) * 1024 + n] = (bf16_t)acc[r][c][v];
                } else if (n < 2048) {
                    int h = (n - 1024) >> 6, d = (n - 1024) & 63;
                    bf16_t* p = kc + ((size_t)(bb * 16 + h) * Tq + t) * 64 + d;
                    #pragma unroll
                    for (int v = 0; v < 4; v++) p[v * 64] = (bf16_t)acc[r][c][v];
                } else {
                    int h = (n - 2048) >> 6, d = (n - 2048) & 63;
                    bf16x4 o;
                    #pragma unroll
                    for (int v = 0; v < 4; v++) o[v] = (bf16_t)acc[r][c][v];
                    *(bf16x4*)&vtp[((size_t)(bb * 16 + h) * 64 + d) * Tq + t] = o;
                }
            }
        }
    }
}

// ---------- attention: R6 structure FROZEN (Q=64/block, compact K/V, 4-way k-split) ----
// Proven local optimum: Q=128/block loses occupancy (R7: 12%, 74us), barrier-free
// direct-global serializes on L2 latency (R4), reg clamp spills (R5).
__global__ __launch_bounds__(256)
void attn_kernel(const bf16_t* __restrict__ Qc, const bf16_t* __restrict__ Kc,
                 const bf16_t* __restrict__ Vt,
                 bf16_t* __restrict__ Op0, bf16_t* __restrict__ Op1,
                 bf16_t* __restrict__ Op2, bf16_t* __restrict__ Op3,
                 float* __restrict__ n2part) {
    __shared__ __align__(16) bf16_t Ks[64 * 64];  // swizzled [key][d]
    __shared__ __align__(16) bf16_t Vs[64 * 64];  // swizzled [d][key]
    __shared__ __align__(16) bf16_t Ws[64 * 64];  // swizzled [q][key]

    const int tid = threadIdx.x;
    const int wave = tid >> 6;
    const int lane = tid & 63;
    const int lrow = lane & 15;
    const int lg   = lane >> 4;     // 0..3
    const int er = lg * 4;
    const int ec = lane & 15;

    const int raw     = blockIdx.x;       // 0..127, heavy-first
    const int qi      = 31 - (raw >> 2);
    const int quarter = raw & 3;
    const int q0      = qi * 64;
    const int bh = blockIdx.y;
    const int b = bh >> 4, h = bh & 15;

    const int nt = qi + 1;
    const int lo = (quarter * nt) >> 2;
    const int hi = ((quarter + 1) * nt) >> 2;

    const bf16_t* Qb = Qc + (size_t)b * Tq * Cq + h * 64;
    const bf16_t* Kb = Kc + (size_t)bh * Tq * 64;
    const bf16_t* Vb = Vt + (size_t)bh * 64 * Tq;

    // Q fragments (B-operand for S^T)
    bf16x8 qf[2];
    {
        const bf16_t* qrow = Qb + (size_t)(q0 + wave * 16 + lrow) * Cq + lg * 8;
        qf[0] = *(const bf16x8*)(qrow);
        qf[1] = *(const bf16x8*)(qrow + 32);
    }

    // staging slots (swizzled): thread covers slots tid and tid+256
    const int s0 = tid, s1 = tid + 256;
    const int r0 = s0 >> 3, cg0 = (s0 & 7) ^ (r0 & 7);
    const int r1 = s1 >> 3, cg1 = (s1 & 7) ^ (r1 & 7);

    bf16x8 kr0, kr1, vr0, vr1;
    if (lo < hi) {
        const int key0 = lo * 64;
        kr0 = *(const bf16x8*)&Kb[(size_t)(key0 + r0) * 64 + cg0 * 8];
        kr1 = *(const bf16x8*)&Kb[(size_t)(key0 + r1) * 64 + cg1 * 8];
        vr0 = *(const bf16x8*)&Vb[(size_t)r0 * Tq + key0 + cg0 * 8];
        vr1 = *(const bf16x8*)&Vb[(size_t)r1 * Tq + key0 + cg1 * 8];
    }

    f32x4 oacc[4] = {};
    float n2 = 0.f;
    const float C1 = 0.18033688f;  // 0.125 * log2(e)

    for (int kt = lo; kt < hi; kt++) {
        __syncthreads();  // all waves done reading LDS from previous iteration
        *(bf16x8*)&Ks[s0 * 8] = kr0;   // compiler waits vmcnt on the prefetch here
        *(bf16x8*)&Ks[s1 * 8] = kr1;
        *(bf16x8*)&Vs[s0 * 8] = vr0;
        *(bf16x8*)&Vs[s1 * 8] = vr1;
        __syncthreads();

        if (kt + 1 < hi) {  // prefetch next tile; in flight during compute below
            const int k1 = (kt + 1) * 64;
            kr0 = *(const bf16x8*)&Kb[(size_t)(k1 + r0) * 64 + cg0 * 8];
            kr1 = *(const bf16x8*)&Kb[(size_t)(k1 + r1) * 64 + cg1 * 8];
            vr0 = *(const bf16x8*)&Vb[(size_t)r0 * Tq + k1 + cg0 * 8];
            vr1 = *(const bf16x8*)&Vb[(size_t)r1 * Tq + k1 + cg1 * 8];
        }

        // S^T = K Q^T : C-layout gives lane 4 consecutive KEYS (rows) for one q (col)
        f32x4 sacc[4];
        #pragma unroll
        for (int j = 0; j < 4; j++) {
            int r = j * 16 + lrow;
            bf16x8 kf0 = *(const bf16x8*)&Ks[SWZ(r, lg)];
            bf16x8 kf1 = *(const bf16x8*)&Ks[SWZ(r, 4 + lg)];
            f32x4 z = {};
            z = MFMA_BF16(kf0, qf[0], z);
            sacc[j] = MFMA_BF16(kf1, qf[1], z);
        }

        // softplus in log2 domain: w' = max(t,0) + log2(1 + 2^-|t|), t = s*0.125*log2e
        const bool diag = (kt == qi);  // wave-uniform branch
        #pragma unroll
        for (int j = 0; j < 4; j++) {
            bf16x4 wb;
            #pragma unroll
            for (int v = 0; v < 4; v++) {
                float t = sacc[j][v] * C1;
                float e = __builtin_amdgcn_exp2f(-fabsf(t));
                float w = fmaxf(t, 0.f) + __builtin_amdgcn_logf(1.f + e);  // v_log = log2
                if (diag && (j * 16 + er + v > wave * 16 + ec)) w = 0.f;   // key > q
                n2 += w * w;
                wb[v] = (bf16_t)w;
            }
            // 4 consecutive keys, one q: packed b64 write
            *(bf16x4*)&Ws[SWZ(wave * 16 + ec, 2 * j + (lg >> 1)) + (lg & 1) * 4] = wb;
        }

        // O += W V  (Ws written/read by same wave only -> DS pipe in-order, no barrier)
        #pragma unroll
        for (int s2 = 0; s2 < 2; s2++) {
            bf16x8 wf = *(const bf16x8*)&Ws[SWZ(wave * 16 + lrow, s2 * 4 + lg)];
            #pragma unroll
            for (int jd = 0; jd < 4; jd++) {
                bf16x8 vf = *(const bf16x8*)&Vs[SWZ(jd * 16 + lrow, s2 * 4 + lg)];
                oacc[jd] = MFMA_BF16(wf, vf, oacc[jd]);
            }
        }
    }

    // n2 lives per lane for q = wave*16+ec; reduce over the 4 lane-groups
    n2 += __shfl_xor(n2, 16, 64);
    n2 += __shfl_xor(n2, 32, 64);

    // partial epilogue (unconditional: zero-iteration blocks must write zeros over poison)
    bf16_t* Op = (quarter == 0 ? Op0 : quarter == 1 ? Op1 : quarter == 2 ? Op2 : Op3)
               + ((size_t)bh * 32 + qi) * 4096;
    #pragma unroll
    for (int jd = 0; jd < 4; jd++) {
        #pragma unroll
        for (int v = 0; v < 4; v++) {
            Op[(wave * 16 + er + v) * 64 + jd * 16 + ec] = (bf16_t)oacc[jd][v];
        }
    }
    if (lg == 0) {
        n2part[((size_t)quarter * 1024 + bh * 32 + qi) * 64 + wave * 16 + ec] = n2;
    }
}

// ---------- combine 4 partials: ao = (ΣO) * rsqrt(Σn2) ----------
__global__ __launch_bounds__(256)
void combine_kernel(const bf16_t* __restrict__ O0, const bf16_t* __restrict__ O1,
                    const bf16_t* __restrict__ O2, const bf16_t* __restrict__ O3,
                    const float* __restrict__ n2part, bf16_t* __restrict__ ao) {
    const int qi = blockIdx.x;
    const int bh = blockIdx.y;
    const int b = bh >> 4, h = bh & 15;
    const int t = threadIdx.x;
    const size_t base = ((size_t)bh * 32 + qi) * 4096;
    const float* np = n2part + ((size_t)bh * 32 + qi) * 64;
    #pragma unroll
    for (int i = 0; i < 2; i++) {
        int idx = i * 2048 + t * 8;
        int row = idx >> 6, col = idx & 63;
        bf16x8 a0 = *(const bf16x8*)(O0 + base + idx);
        bf16x8 a1 = *(const bf16x8*)(O1 + base + idx);
        bf16x8 a2 = *(const bf16x8*)(O2 + base + idx);
        bf16x8 a3 = *(const bf16x8*)(O3 + base + idx);
        float nsum = np[row] + np[(size_t)1024 * 64 + row]
                   + np[(size_t)2048 * 64 + row] + np[(size_t)3072 * 64 + row];
        float inv = rsqrtf(nsum);
        bf16x8 o;
        #pragma unroll
        for (int j = 0; j < 8; j++)
            o[j] = (bf16_t)(((float)a0[j] + (float)a1[j] + (float)a2[j] + (float)a3[j]) * inv);
        *(bf16x8*)(ao + (size_t)(b * Tq + qi * 64 + row) * Cq + h * HSq + col) = o;
    }
}

// ---------- launch ----------
extern "C" void kernel_launch(void* const* d_in, const int* in_sizes, int n_in,
                              void* d_out, int out_size, void* d_ws, size_t ws_size,
                              hipStream_t stream) {
    const float* x     = (const float*)d_in[0];
    const float* wqkv  = (const float*)d_in[1];
    const float* wproj = (const float*)d_in[2];
    const float* bproj = (const float*)d_in[3];
    float* out = (float*)d_out;

    // workspace lifetime plan (64 MB):
    //  phase1 cvt+gemm1: wprojb[0,2) xb[2,10) wqkvb[10,16) qcb[16,24) kcb[24,32) vtb[32,40)
    //  phase2 attn:      op0 over dead xb[2,10), n2 over dead wqkvb[10,11), op1[40,48)
    //                    op2[48,56) op3[56,64)
    //  phase3 combine:   ao over dead kcb[24,32)
    //  phase4 gemm2:     reads ao[24,32) + wprojb[0,2)
    char* ws = (char*)d_ws;
    bf16_t* wprojb = (bf16_t*)(ws);
    bf16_t* xb     = (bf16_t*)(ws + ( 2u << 20));
    bf16_t* wqkvb  = (bf16_t*)(ws + (10u << 20));
    bf16_t* qcb    = (bf16_t*)(ws + (16u << 20));
    bf16_t* kcb    = (bf16_t*)(ws + (24u << 20));
    bf16_t* vtb    = (bf16_t*)(ws + (32u << 20));
    bf16_t* opart0 = (bf16_t*)(ws + ( 2u << 20));
    float*  n2part = (float*)(ws + (10u << 20));
    bf16_t* opart1 = (bf16_t*)(ws + (40u << 20));
    bf16_t* opart2 = (bf16_t*)(ws + (48u << 20));
    bf16_t* opart3 = (bf16_t*)(ws + (56u << 20));
    bf16_t* aob    = (bf16_t*)(ws + (24u << 20));

    cvt_all<<<8192, 256, 0, stream>>>(x, wqkv, wproj, xb, wqkvb, wprojb);

    // QKV projection with fused layout epilogue: Qc / Kc / V^T  (BK=64 swizzled)
    gemm_bt<128, 2><<<dim3(24, 32), 256, 0, stream>>>(xb, wqkvb, nullptr, nullptr,
                                                      qcb, kcb, vtb, Mrows, 3 * Cq, Cq);
    // attention (R6 frozen structure, 4-way k-split, 4096 blocks) + combine
    attn_kernel<<<dim3(128, 32), 256, 0, stream>>>(qcb, kcb, vtb,
                                                   opart0, opart1, opart2, opart3, n2part);
    combine_kernel<<<dim3(32, 32), 256, 0, stream>>>(opart0, opart1, opart2, opart3,
                                                     n2part, aob);
    // output projection + bias (BK=64 swizzled)
    gemm_bt<64, 1><<<dim3(8, 64), 256, 0, stream>>>(aob, wprojb, (void*)out, bproj,
                                                    nullptr, nullptr, nullptr, Mrows, Cq, Cq);
}